// Round 7
// baseline (2797.300 us; speedup 1.0000x reference)
//
#include <hip/hip_runtime.h>

// Problem constants
#define NUM_EMB 1024
#define EMB_DIM 256
#define BATCH   32
#define HW      1024
#define Z_ELEMS (BATCH*EMB_DIM*HW)   // 8388608
#define LOSS_OFF Z_ELEMS
#define IDX_OFF (Z_ELEMS+1)

// ws layout: float[0] loss acc, uint[1] ticket, floats [16..1040) cnorm;
// packed u64 argmin partials at byte 262144 (if ws fits).
#define WS_CNORM_OFF 16
#define WS_PACKED_BYTE_OFF 262144
#define WS_NEEDED (WS_PACKED_BYTE_OFF + 32768*8)

// ---------------------------------------------------------------------------
// K0: blocks 0..3: cnorm[k] = sum_d cb[k][d]^2 via numpy's exact pairwise tree
// (fp32, squares rounded separately, no fma contraction). Blocks 4..131: init
// packed[n] = u64max. Thread 0 zeroes loss acc + ticket.
__global__ __launch_bounds__(256) void k_prep(const float* __restrict__ cb,
                                              float* __restrict__ ws,
                                              unsigned long long* __restrict__ packed) {
    const int tid = threadIdx.x;
    if (blockIdx.x == 0 && tid == 0) { ws[0] = 0.0f; ((unsigned int*)ws)[1] = 0u; }
    if (blockIdx.x < 4) {
        int k = blockIdx.x * 256 + tid;
        const float* row = cb + (size_t)k * EMB_DIM;
        float half[2];
#pragma unroll
        for (int h = 0; h < 2; ++h) {
            const float* a = row + h * 128;
            float r[8];
#pragma unroll
            for (int j = 0; j < 8; ++j) r[j] = __fmul_rn(a[j], a[j]);
            for (int i = 8; i < 128; i += 8)
#pragma unroll
                for (int j = 0; j < 8; ++j)
                    r[j] = __fadd_rn(r[j], __fmul_rn(a[i + j], a[i + j]));
            half[h] = __fadd_rn(__fadd_rn(__fadd_rn(r[0], r[1]), __fadd_rn(r[2], r[3])),
                                __fadd_rn(__fadd_rn(r[4], r[5]), __fadd_rn(r[6], r[7])));
        }
        ws[WS_CNORM_OFF + k] = __fadd_rn(half[0], half[1]);
    } else {
        packed[(blockIdx.x - 4) * 256 + tid] = 0xFFFFFFFFFFFFFFFFull;
    }
}

// ---------------------------------------------------------------------------
// K1: distance argmin over ONE 256-code slab (k-split 4-way for occupancy:
// 1024 blocks = 4/CU = 4 waves/SIMD; VGPR 128 x 16 waves = full 512/SIMD).
// Reference fp32 rounding: d = fl( fl(z2+c2) - fl(2*dot) ), dot = serial
// ascending-d fma per (n,k). 8m x 16k per-thread tile (fma:ds_read_b128 =
// 21.3). znorm computed in-kernel from the staged z tiles (exact numpy
// pairwise tree; every block computes it — redundant x4 but ~1% cost).
// Packed (val<<32|idx) u64 atomicMin merges the 4 slab partials per query.
#define MT 128
#define DC 16
#define CPAD 260

__global__ __launch_bounds__(256, 4) void k_argmin(const float* __restrict__ z,
                                                   const float* __restrict__ cb,
                                                   const float* __restrict__ ws,
                                                   unsigned long long* __restrict__ packed) {
    __shared__ __attribute__((aligned(16))) float z_buf[DC * MT];    // 8 KB
    __shared__ __attribute__((aligned(16))) float c_buf[DC * CPAD];  // 16.6 KB
    __shared__ float sh_half[2 * MT];                                // 1 KB
    __shared__ float zn_s[MT];                                       // 0.5 KB

    const int tid = threadIdx.x;
    const int tx = tid & 15;          // k: 16 codes (j*64 + tx*4 + c)
    const int ty = tid >> 4;          // m: positions ty*8 .. ty*8+7
    const int b  = blockIdx.y;
    const int p0 = blockIdx.x * MT;
    const int k0 = blockIdx.z * 256;  // this block's code slab

    const float* zb = z + (size_t)b * EMB_DIM * HW + p0;
    const float* cn = ws + WS_CNORM_OFF;

    float minv[8];
    int   mini[8];
#pragma unroll
    for (int a = 0; a < 8; ++a) { minv[a] = 3.402823466e+38f; mini[a] = 0; }

    // znorm accumulators (numpy tree chains), built from staged z tiles
    float r[8];
#pragma unroll
    for (int j = 0; j < 8; ++j) r[j] = 0.0f;
    const int znp = tid & 127;        // position this thread's znorm covers
    const int znh = tid >> 7;         // which 128-d half (wave-uniform)

    // staging coords (loop-invariant)
    const int zrow = tid >> 4;            // 0..15 (d row)
    const int zcol = (tid & 15) << 3;     // 0..120 (2 float4)
    const int ckk  = tid >> 2;            // 0..63 (c row within pass group)
    const int cseg = tid & 3;             // float4 slot within 16-d span

    // prefetch chunk 0 (dc=0)
    float4 zpre0 = *(const float4*)(zb + (size_t)zrow * HW + zcol);
    float4 zpre1 = *(const float4*)(zb + (size_t)zrow * HW + zcol + 4);
    float4 cpre[4];
#pragma unroll
    for (int p = 0; p < 4; ++p)
        cpre[p] = *(const float4*)(cb + (size_t)(k0 + p * 64 + ckk) * EMB_DIM + cseg * 4);

    float acc[8][16];
#pragma unroll
    for (int a = 0; a < 8; ++a)
#pragma unroll
        for (int q = 0; q < 16; ++q) acc[a][q] = 0.0f;

#pragma unroll 1
    for (int t = 0; t < DC; ++t) {
        __syncthreads();   // previous compute done; LDS reusable
        *(float4*)(z_buf + zrow * MT + zcol)     = zpre0;
        *(float4*)(z_buf + zrow * MT + zcol + 4) = zpre1;
#pragma unroll
        for (int p = 0; p < 4; ++p) {
            int kk = p * 64 + ckk;
            c_buf[(cseg * 4 + 0) * CPAD + kk] = cpre[p].x;
            c_buf[(cseg * 4 + 1) * CPAD + kk] = cpre[p].y;
            c_buf[(cseg * 4 + 2) * CPAD + kk] = cpre[p].z;
            c_buf[(cseg * 4 + 3) * CPAD + kk] = cpre[p].w;
        }
        // prefetch chunk t+1 (after staging, before barrier)
        if (t < DC - 1) {
            const int d2 = (t + 1) * 16;
            zpre0 = *(const float4*)(zb + (size_t)(d2 + zrow) * HW + zcol);
            zpre1 = *(const float4*)(zb + (size_t)(d2 + zrow) * HW + zcol + 4);
#pragma unroll
            for (int p = 0; p < 4; ++p)
                cpre[p] = *(const float4*)(cb + (size_t)(k0 + p * 64 + ckk) * EMB_DIM + d2 + cseg * 4);
        }
        __syncthreads();   // LDS writes visible

#pragma unroll 2
        for (int d = 0; d < 16; ++d) {
            float4 za0 = *(const float4*)(z_buf + d * MT + ty * 8);
            float4 za1 = *(const float4*)(z_buf + d * MT + ty * 8 + 4);
            float zf[8] = {za0.x, za0.y, za0.z, za0.w, za1.x, za1.y, za1.z, za1.w};
#pragma unroll
            for (int j = 0; j < 4; ++j) {
                float4 cv = *(const float4*)(c_buf + d * CPAD + j * 64 + tx * 4);
#pragma unroll
                for (int a = 0; a < 8; ++a) {
                    acc[a][j * 4 + 0] = fmaf(zf[a], cv.x, acc[a][j * 4 + 0]);
                    acc[a][j * 4 + 1] = fmaf(zf[a], cv.y, acc[a][j * 4 + 1]);
                    acc[a][j * 4 + 2] = fmaf(zf[a], cv.z, acc[a][j * 4 + 2]);
                    acc[a][j * 4 + 3] = fmaf(zf[a], cv.w, acc[a][j * 4 + 3]);
                }
            }
        }

        // znorm chains from this z tile (wave-uniform half match).
        // chunk t covers dims t*16..t*16+15; chain j = e & 7 keeps numpy order.
        if ((t >> 3) == znh) {
#pragma unroll
            for (int e = 0; e < 16; ++e) {
                float v = z_buf[e * MT + znp];
                r[e & 7] = __fadd_rn(r[e & 7], __fmul_rn(v, v));
            }
        }
    }

    // finish znorm: combine chains exactly like numpy's tree
    {
        float s01 = __fadd_rn(__fadd_rn(r[0], r[1]), __fadd_rn(r[2], r[3]));
        float s23 = __fadd_rn(__fadd_rn(r[4], r[5]), __fadd_rn(r[6], r[7]));
        sh_half[znh * MT + znp] = __fadd_rn(s01, s23);
        __syncthreads();
        if (tid < MT) zn_s[tid] = __fadd_rn(sh_half[tid], sh_half[MT + tid]);
        __syncthreads();
    }

    // fold slab's 256 codes into argmin (reference rounding)
    {
        float c2[16];
#pragma unroll
        for (int j = 0; j < 4; ++j)
#pragma unroll
            for (int c = 0; c < 4; ++c)
                c2[j * 4 + c] = cn[k0 + j * 64 + tx * 4 + c];
        float z2[8];
#pragma unroll
        for (int a = 0; a < 8; ++a) z2[a] = zn_s[ty * 8 + a];
#pragma unroll
        for (int a = 0; a < 8; ++a) {
#pragma unroll
            for (int j = 0; j < 4; ++j) {
#pragma unroll
                for (int c = 0; c < 4; ++c) {      // kg ascending per thread
                    int kg = k0 + j * 64 + tx * 4 + c;
                    float t1 = __fadd_rn(z2[a], c2[j * 4 + c]);
                    float s  = __fadd_rn(t1, __fmul_rn(-2.0f, acc[a][j * 4 + c]));
                    if (s < minv[a]) { minv[a] = s; mini[a] = kg; }  // strict <
                }
            }
        }
    }

    // cross-tx reduction (reuse c_buf: 2048 floats + 2048 ints <= 4160)
    __syncthreads();
    float* rv = c_buf;
    int*   ri = (int*)(c_buf + 2048);
#pragma unroll
    for (int a = 0; a < 8; ++a) {
        int m = ty * 8 + a;
        rv[m * 16 + tx] = minv[a];
        ri[m * 16 + tx] = mini[a];
    }
    __syncthreads();
    if (tid < MT) {
        int m = tid;
        float bv = rv[m * 16];
        int   bi = ri[m * 16];
#pragma unroll
        for (int j = 1; j < 16; ++j) {
            float v  = rv[m * 16 + j];
            int   i2 = ri[m * 16 + j];
            if (v < bv || (v == bv && i2 < bi)) { bv = v; bi = i2; }
        }
        int n = b * HW + p0 + m;
        unsigned long long pk = ((unsigned long long)__float_as_uint(bv) << 32)
                                | (unsigned long long)(unsigned)bi;
        atomicMin(&packed[n], pk);
    }
}

// ---------------------------------------------------------------------------
// K1b (fallback only, when packed lives in out's z-region): extract indices.
__global__ __launch_bounds__(256) void k_merge(const unsigned long long* __restrict__ packed,
                                               float* __restrict__ out) {
    int n = blockIdx.x * 256 + threadIdx.x;
    out[IDX_OFF + n] = (float)(int)(unsigned)(packed[n] & 0xFFFFFFFFull);
}

// ---------------------------------------------------------------------------
// K2: gather z_q via LDS-staged codebook rows (coalesced cb reads), write
// straight-through out = fl(z + fl(z_q - z)), loss partials; fused index
// extraction + fused final scale via ticket counter.
__global__ __launch_bounds__(256) void k_gather(const float* __restrict__ z,
                                                const float* __restrict__ cb,
                                                float* __restrict__ out,
                                                float* __restrict__ ws,
                                                const unsigned long long* __restrict__ packed,
                                                int fused_idx) {
    __shared__ float s_cb[64][65];   // 16.6 KB, stride 65 -> 2-way max on reads
    __shared__ int   s_idx[64];
    __shared__ float s_red[4];
    const int tid = threadIdx.x;
    const int b  = blockIdx.x >> 4;
    const int p0 = (blockIdx.x & 15) * 64;

    if (tid < 64) {
        int n = b * HW + p0 + tid;
        int bi;
        if (fused_idx) {
            bi = (int)(unsigned)(packed[n] & 0xFFFFFFFFull);
            out[IDX_OFF + n] = (float)bi;
        } else {
            bi = (int)out[IDX_OFF + n];
        }
        s_idx[tid] = bi;
    }
    __syncthreads();

    const int p    = tid & 63;
    const int cgrp = tid >> 6;        // 0..3
    const int row  = tid >> 2;        // staging: row 0..63
    const int q4   = tid & 3;         // staging: float4 slot group
    const float* zrow = z   + (size_t)b * EMB_DIM * HW + p0 + p;
    float*       orow = out + (size_t)b * EMB_DIM * HW + p0 + p;

    float acc = 0.0f;
#pragma unroll 1
    for (int d0 = 0; d0 < EMB_DIM; d0 += 64) {
        const float* cr = cb + (size_t)s_idx[row] * EMB_DIM + d0;
#pragma unroll
        for (int pass = 0; pass < 4; ++pass) {
            int c = q4 * 4 + pass * 16;
            *(float4*)(&s_cb[row][c]) = *(const float4*)(cr + c);
        }
        __syncthreads();
#pragma unroll
        for (int j = 0; j < 16; ++j) {
            int c = cgrp * 16 + j;
            float zq = s_cb[p][c];
            float zv = zrow[(size_t)(d0 + c) * HW];
            float d  = zq - zv;
            orow[(size_t)(d0 + c) * HW] = zv + d;
            acc += d * d;
        }
        __syncthreads();   // before re-staging s_cb
    }
#pragma unroll
    for (int off = 32; off > 0; off >>= 1) acc += __shfl_down(acc, off, 64);
    if ((tid & 63) == 0) s_red[tid >> 6] = acc;
    __syncthreads();
    if (tid == 0) {
        atomicAdd(ws, s_red[0] + s_red[1] + s_red[2] + s_red[3]);
        __threadfence();
        unsigned old = atomicAdd((unsigned int*)ws + 1, 1u);
        if (old == 511u) {   // last block: all 512 loss adds visible
            float total = atomicAdd(ws, 0.0f);
            out[LOSS_OFF] = 1.25f * (total * (1.0f / 8388608.0f));
        }
    }
}

// ---------------------------------------------------------------------------
extern "C" void kernel_launch(void* const* d_in, const int* in_sizes, int n_in,
                              void* d_out, int out_size, void* d_ws, size_t ws_size,
                              hipStream_t stream) {
    const float* z  = (const float*)d_in[0];
    const float* cb = (const float*)d_in[1];
    float* out = (float*)d_out;
    float* ws  = (float*)d_ws;

    const bool big_ws = (ws_size >= (size_t)WS_NEEDED);
    unsigned long long* packed = big_ws
        ? (unsigned long long*)((char*)d_ws + WS_PACKED_BYTE_OFF)
        : (unsigned long long*)d_out;   // stage in out's z-region, merge before gather

    k_prep  <<<132, 256, 0, stream>>>(cb, ws, packed);
    k_argmin<<<dim3(HW / MT, BATCH, 4), 256, 0, stream>>>(z, cb, ws, packed);
    if (!big_ws)
        k_merge<<<BATCH * HW / 256, 256, 0, stream>>>(packed, out);
    k_gather<<<BATCH * (HW / 64), 256, 0, stream>>>(z, cb, out, ws, packed, big_ws ? 1 : 0);
}

// Round 8
// 328.991 us; speedup vs baseline: 8.5027x; 8.5027x over previous
//
#include <hip/hip_runtime.h>

// Problem constants
#define NUM_EMB 1024
#define EMB_DIM 256
#define BATCH   32
#define HW      1024
#define Z_ELEMS (BATCH*EMB_DIM*HW)   // 8388608
#define LOSS_OFF Z_ELEMS
#define IDX_OFF (Z_ELEMS+1)

// ws layout: float[0] loss acc, uint[1] ticket, floats [16..1040) cnorm;
// packed u64 argmin partials at byte 262144 (if ws fits).
#define WS_CNORM_OFF 16
#define WS_PACKED_BYTE_OFF 262144
#define WS_NEEDED (WS_PACKED_BYTE_OFF + 32768*8)

// ---------------------------------------------------------------------------
// K0: blocks 0..3: cnorm[k] = sum_d cb[k][d]^2 via numpy's exact pairwise tree
// (fp32, squares rounded separately, no fma contraction). Blocks 4..131: init
// packed[n] = u64max. Thread 0 zeroes loss acc + ticket.
__global__ __launch_bounds__(256) void k_prep(const float* __restrict__ cb,
                                              float* __restrict__ ws,
                                              unsigned long long* __restrict__ packed) {
    const int tid = threadIdx.x;
    if (blockIdx.x == 0 && tid == 0) { ws[0] = 0.0f; ((unsigned int*)ws)[1] = 0u; }
    if (blockIdx.x < 4) {
        int k = blockIdx.x * 256 + tid;
        const float* row = cb + (size_t)k * EMB_DIM;
        float half[2];
#pragma unroll
        for (int h = 0; h < 2; ++h) {
            const float* a = row + h * 128;
            float r[8];
#pragma unroll
            for (int j = 0; j < 8; ++j) r[j] = __fmul_rn(a[j], a[j]);
            for (int i = 8; i < 128; i += 8)
#pragma unroll
                for (int j = 0; j < 8; ++j)
                    r[j] = __fadd_rn(r[j], __fmul_rn(a[i + j], a[i + j]));
            half[h] = __fadd_rn(__fadd_rn(__fadd_rn(r[0], r[1]), __fadd_rn(r[2], r[3])),
                                __fadd_rn(__fadd_rn(r[4], r[5]), __fadd_rn(r[6], r[7])));
        }
        ws[WS_CNORM_OFF + k] = __fadd_rn(half[0], half[1]);
    } else {
        packed[(blockIdx.x - 4) * 256 + tid] = 0xFFFFFFFFFFFFFFFFull;
    }
}

// ---------------------------------------------------------------------------
// K1: distance argmin over ONE 256-code slab (k-split 4-way: 1024 blocks).
// __launch_bounds__(256,2): do NOT force 4 waves/EU — that caps VGPR at 64
// and spills the 128-float acc array (R7: 9.8 GB scratch traffic, 13x slower).
// At the natural VGPR=128, 4 waves/SIMD = the full 512-reg pool, so the
// 1024-block grid still reaches 4 blocks/CU.
// Reference fp32 rounding: d = fl( fl(z2+c2) - fl(2*dot) ), dot = serial
// ascending-d fma per (n,k). 8m x 16k per-thread tile (fma:ds_read_b128 =
// 21.3). znorm computed in-kernel from the staged z tiles (exact numpy
// pairwise tree; redundant x4 across k-slabs, ~1% cost).
// Packed (val<<32|idx) u64 atomicMin merges the 4 slab partials per query.
#define MT 128
#define DC 16
#define CPAD 260

__global__ __launch_bounds__(256, 2) void k_argmin(const float* __restrict__ z,
                                                   const float* __restrict__ cb,
                                                   const float* __restrict__ ws,
                                                   unsigned long long* __restrict__ packed) {
    __shared__ __attribute__((aligned(16))) float z_buf[DC * MT];    // 8 KB
    __shared__ __attribute__((aligned(16))) float c_buf[DC * CPAD];  // 16.6 KB
    __shared__ float sh_half[2 * MT];                                // 1 KB
    __shared__ float zn_s[MT];                                       // 0.5 KB

    const int tid = threadIdx.x;
    const int tx = tid & 15;          // k: 16 codes (j*64 + tx*4 + c)
    const int ty = tid >> 4;          // m: positions ty*8 .. ty*8+7
    const int b  = blockIdx.y;
    const int p0 = blockIdx.x * MT;
    const int k0 = blockIdx.z * 256;  // this block's code slab

    const float* zb = z + (size_t)b * EMB_DIM * HW + p0;
    const float* cn = ws + WS_CNORM_OFF;

    float minv[8];
    int   mini[8];
#pragma unroll
    for (int a = 0; a < 8; ++a) { minv[a] = 3.402823466e+38f; mini[a] = 0; }

    // znorm accumulators (numpy tree chains), built from staged z tiles
    float r[8];
#pragma unroll
    for (int j = 0; j < 8; ++j) r[j] = 0.0f;
    const int znp = tid & 127;        // position this thread's znorm covers
    const int znh = tid >> 7;         // which 128-d half (wave-uniform)

    // staging coords (loop-invariant)
    const int zrow = tid >> 4;            // 0..15 (d row)
    const int zcol = (tid & 15) << 3;     // 0..120 (2 float4)
    const int ckk  = tid >> 2;            // 0..63 (c row within pass group)
    const int cseg = tid & 3;             // float4 slot within 16-d span

    // prefetch chunk 0 (dc=0)
    float4 zpre0 = *(const float4*)(zb + (size_t)zrow * HW + zcol);
    float4 zpre1 = *(const float4*)(zb + (size_t)zrow * HW + zcol + 4);
    float4 cpre[4];
#pragma unroll
    for (int p = 0; p < 4; ++p)
        cpre[p] = *(const float4*)(cb + (size_t)(k0 + p * 64 + ckk) * EMB_DIM + cseg * 4);

    float acc[8][16];
#pragma unroll
    for (int a = 0; a < 8; ++a)
#pragma unroll
        for (int q = 0; q < 16; ++q) acc[a][q] = 0.0f;

#pragma unroll 1
    for (int t = 0; t < DC; ++t) {
        __syncthreads();   // previous compute done; LDS reusable
        *(float4*)(z_buf + zrow * MT + zcol)     = zpre0;
        *(float4*)(z_buf + zrow * MT + zcol + 4) = zpre1;
#pragma unroll
        for (int p = 0; p < 4; ++p) {
            int kk = p * 64 + ckk;
            c_buf[(cseg * 4 + 0) * CPAD + kk] = cpre[p].x;
            c_buf[(cseg * 4 + 1) * CPAD + kk] = cpre[p].y;
            c_buf[(cseg * 4 + 2) * CPAD + kk] = cpre[p].z;
            c_buf[(cseg * 4 + 3) * CPAD + kk] = cpre[p].w;
        }
        // prefetch chunk t+1 (after staging, before barrier)
        if (t < DC - 1) {
            const int d2 = (t + 1) * 16;
            zpre0 = *(const float4*)(zb + (size_t)(d2 + zrow) * HW + zcol);
            zpre1 = *(const float4*)(zb + (size_t)(d2 + zrow) * HW + zcol + 4);
#pragma unroll
            for (int p = 0; p < 4; ++p)
                cpre[p] = *(const float4*)(cb + (size_t)(k0 + p * 64 + ckk) * EMB_DIM + d2 + cseg * 4);
        }
        __syncthreads();   // LDS writes visible

#pragma unroll 2
        for (int d = 0; d < 16; ++d) {
            float4 za0 = *(const float4*)(z_buf + d * MT + ty * 8);
            float4 za1 = *(const float4*)(z_buf + d * MT + ty * 8 + 4);
            float zf[8] = {za0.x, za0.y, za0.z, za0.w, za1.x, za1.y, za1.z, za1.w};
#pragma unroll
            for (int j = 0; j < 4; ++j) {
                float4 cv = *(const float4*)(c_buf + d * CPAD + j * 64 + tx * 4);
#pragma unroll
                for (int a = 0; a < 8; ++a) {
                    acc[a][j * 4 + 0] = fmaf(zf[a], cv.x, acc[a][j * 4 + 0]);
                    acc[a][j * 4 + 1] = fmaf(zf[a], cv.y, acc[a][j * 4 + 1]);
                    acc[a][j * 4 + 2] = fmaf(zf[a], cv.z, acc[a][j * 4 + 2]);
                    acc[a][j * 4 + 3] = fmaf(zf[a], cv.w, acc[a][j * 4 + 3]);
                }
            }
        }

        // znorm chains from this z tile (wave-uniform half match).
        // chunk t covers dims t*16..t*16+15; chain j = e & 7 keeps numpy order.
        if ((t >> 3) == znh) {
#pragma unroll
            for (int e = 0; e < 16; ++e) {
                float v = z_buf[e * MT + znp];
                r[e & 7] = __fadd_rn(r[e & 7], __fmul_rn(v, v));
            }
        }
    }

    // finish znorm: combine chains exactly like numpy's tree
    {
        float s01 = __fadd_rn(__fadd_rn(r[0], r[1]), __fadd_rn(r[2], r[3]));
        float s23 = __fadd_rn(__fadd_rn(r[4], r[5]), __fadd_rn(r[6], r[7]));
        sh_half[znh * MT + znp] = __fadd_rn(s01, s23);
        __syncthreads();
        if (tid < MT) zn_s[tid] = __fadd_rn(sh_half[tid], sh_half[MT + tid]);
        __syncthreads();
    }

    // fold slab's 256 codes into argmin (reference rounding)
    {
        float c2[16];
#pragma unroll
        for (int j = 0; j < 4; ++j)
#pragma unroll
            for (int c = 0; c < 4; ++c)
                c2[j * 4 + c] = cn[k0 + j * 64 + tx * 4 + c];
        float z2[8];
#pragma unroll
        for (int a = 0; a < 8; ++a) z2[a] = zn_s[ty * 8 + a];
#pragma unroll
        for (int a = 0; a < 8; ++a) {
#pragma unroll
            for (int j = 0; j < 4; ++j) {
#pragma unroll
                for (int c = 0; c < 4; ++c) {      // kg ascending per thread
                    int kg = k0 + j * 64 + tx * 4 + c;
                    float t1 = __fadd_rn(z2[a], c2[j * 4 + c]);
                    float s  = __fadd_rn(t1, __fmul_rn(-2.0f, acc[a][j * 4 + c]));
                    if (s < minv[a]) { minv[a] = s; mini[a] = kg; }  // strict <
                }
            }
        }
    }

    // cross-tx reduction (reuse c_buf: 2048 floats + 2048 ints <= 4160)
    __syncthreads();
    float* rv = c_buf;
    int*   ri = (int*)(c_buf + 2048);
#pragma unroll
    for (int a = 0; a < 8; ++a) {
        int m = ty * 8 + a;
        rv[m * 16 + tx] = minv[a];
        ri[m * 16 + tx] = mini[a];
    }
    __syncthreads();
    if (tid < MT) {
        int m = tid;
        float bv = rv[m * 16];
        int   bi = ri[m * 16];
#pragma unroll
        for (int j = 1; j < 16; ++j) {
            float v  = rv[m * 16 + j];
            int   i2 = ri[m * 16 + j];
            if (v < bv || (v == bv && i2 < bi)) { bv = v; bi = i2; }
        }
        int n = b * HW + p0 + m;
        unsigned long long pk = ((unsigned long long)__float_as_uint(bv) << 32)
                                | (unsigned long long)(unsigned)bi;
        atomicMin(&packed[n], pk);
    }
}

// ---------------------------------------------------------------------------
// K1b (fallback only, when packed lives in out's z-region): extract indices.
__global__ __launch_bounds__(256) void k_merge(const unsigned long long* __restrict__ packed,
                                               float* __restrict__ out) {
    int n = blockIdx.x * 256 + threadIdx.x;
    out[IDX_OFF + n] = (float)(int)(unsigned)(packed[n] & 0xFFFFFFFFull);
}

// ---------------------------------------------------------------------------
// K2: gather z_q via LDS-staged codebook rows (coalesced cb reads), write
// straight-through out = fl(z + fl(z_q - z)), loss partials; fused index
// extraction + fused final scale via ticket counter.
__global__ __launch_bounds__(256) void k_gather(const float* __restrict__ z,
                                                const float* __restrict__ cb,
                                                float* __restrict__ out,
                                                float* __restrict__ ws,
                                                const unsigned long long* __restrict__ packed,
                                                int fused_idx) {
    __shared__ float s_cb[64][65];   // 16.6 KB, stride 65 -> 2-way max on reads
    __shared__ int   s_idx[64];
    __shared__ float s_red[4];
    const int tid = threadIdx.x;
    const int b  = blockIdx.x >> 4;
    const int p0 = (blockIdx.x & 15) * 64;

    if (tid < 64) {
        int n = b * HW + p0 + tid;
        int bi;
        if (fused_idx) {
            bi = (int)(unsigned)(packed[n] & 0xFFFFFFFFull);
            out[IDX_OFF + n] = (float)bi;
        } else {
            bi = (int)out[IDX_OFF + n];
        }
        s_idx[tid] = bi;
    }
    __syncthreads();

    const int p    = tid & 63;
    const int cgrp = tid >> 6;        // 0..3
    const int row  = tid >> 2;        // staging: row 0..63
    const int q4   = tid & 3;         // staging: float4 slot group
    const float* zrow = z   + (size_t)b * EMB_DIM * HW + p0 + p;
    float*       orow = out + (size_t)b * EMB_DIM * HW + p0 + p;

    float acc = 0.0f;
#pragma unroll 1
    for (int d0 = 0; d0 < EMB_DIM; d0 += 64) {
        const float* cr = cb + (size_t)s_idx[row] * EMB_DIM + d0;
#pragma unroll
        for (int pass = 0; pass < 4; ++pass) {
            int c = q4 * 4 + pass * 16;
            *(float4*)(&s_cb[row][c]) = *(const float4*)(cr + c);
        }
        __syncthreads();
#pragma unroll
        for (int j = 0; j < 16; ++j) {
            int c = cgrp * 16 + j;
            float zq = s_cb[p][c];
            float zv = zrow[(size_t)(d0 + c) * HW];
            float d  = zq - zv;
            orow[(size_t)(d0 + c) * HW] = zv + d;
            acc += d * d;
        }
        __syncthreads();   // before re-staging s_cb
    }
#pragma unroll
    for (int off = 32; off > 0; off >>= 1) acc += __shfl_down(acc, off, 64);
    if ((tid & 63) == 0) s_red[tid >> 6] = acc;
    __syncthreads();
    if (tid == 0) {
        atomicAdd(ws, s_red[0] + s_red[1] + s_red[2] + s_red[3]);
        __threadfence();
        unsigned old = atomicAdd((unsigned int*)ws + 1, 1u);
        if (old == 511u) {   // last block: all 512 loss adds visible
            float total = atomicAdd(ws, 0.0f);
            out[LOSS_OFF] = 1.25f * (total * (1.0f / 8388608.0f));
        }
    }
}

// ---------------------------------------------------------------------------
extern "C" void kernel_launch(void* const* d_in, const int* in_sizes, int n_in,
                              void* d_out, int out_size, void* d_ws, size_t ws_size,
                              hipStream_t stream) {
    const float* z  = (const float*)d_in[0];
    const float* cb = (const float*)d_in[1];
    float* out = (float*)d_out;
    float* ws  = (float*)d_ws;

    const bool big_ws = (ws_size >= (size_t)WS_NEEDED);
    unsigned long long* packed = big_ws
        ? (unsigned long long*)((char*)d_ws + WS_PACKED_BYTE_OFF)
        : (unsigned long long*)d_out;   // stage in out's z-region, merge before gather

    k_prep  <<<132, 256, 0, stream>>>(cb, ws, packed);
    k_argmin<<<dim3(HW / MT, BATCH, 4), 256, 0, stream>>>(z, cb, ws, packed);
    if (!big_ws)
        k_merge<<<BATCH * HW / 256, 256, 0, stream>>>(packed, out);
    k_gather<<<BATCH * (HW / 64), 256, 0, stream>>>(z, cb, out, ws, packed, big_ws ? 1 : 0);
}

// Round 9
// 304.887 us; speedup vs baseline: 9.1749x; 1.0791x over previous
//
#include <hip/hip_runtime.h>

// Problem constants
#define NUM_EMB 1024
#define EMB_DIM 256
#define BATCH   32
#define HW      1024
#define Z_ELEMS (BATCH*EMB_DIM*HW)   // 8388608
#define LOSS_OFF Z_ELEMS
#define IDX_OFF (Z_ELEMS+1)

// ws: float[0] loss acc, uint[1] ticket, [16..1040) cnorm, [2048..34816) znorm
#define WS_CNORM_OFF 16
#define WS_ZNORM_OFF 2048

// out z-region scratch (all overwritten by k_gather at the very end):
//   bytes [0, 1 MB): Bt — codebook pre-converted to bf16 hi/lo, pre-tiled in
//                    MFMA B-fragment order (slab, chunk, combo, ntile, lane)
//   ints  [262144 .. 294912): cand_cnt[32768]
//   ints  [294912 .. +32768*32): cand[n][32]
#define CNT_IOFF  262144
#define CAND_IOFF 294912
#define CAND_CAP  32
// Threshold: required 2*E_f + 2*E_r = 1.34e-4 (see derivation in analysis);
// 2.5e-4 gives 1.9x margin, ~5 candidates/query expected.
#define T_FILT 2.5e-4f

typedef __attribute__((ext_vector_type(8))) short bf16x8;
typedef __attribute__((ext_vector_type(8))) unsigned short u16x8;
typedef __attribute__((ext_vector_type(4))) float f32x4;

__device__ __forceinline__ unsigned short f2bf_rne(float x) {
    unsigned u = __float_as_uint(x);                 // no NaN in this data
    return (unsigned short)((u + 0x7FFFu + ((u >> 16) & 1u)) >> 16);
}
__device__ __forceinline__ float bf2f(unsigned short h) {
    return __uint_as_float(((unsigned)h) << 16);
}

// ---------------------------------------------------------------------------
// K0: fused prep, 420 blocks.
//  blk 0..3     cnorm[k] via numpy's exact pairwise tree (fp32, no contraction)
//  blk 4..131   znorm[n] same tree (needed for the exact rescore fold)
//  blk 132..163 zero cand_cnt
//  blk 164..419 pack codebook -> Bt (bf16 hi/lo, MFMA-B-fragment tiled)
__global__ __launch_bounds__(256) void k_prep(const float* __restrict__ z,
                                              const float* __restrict__ cb,
                                              float* __restrict__ ws,
                                              float* __restrict__ out) {
    const int tid = threadIdx.x;
    const int blk = blockIdx.x;
    if (blk == 0 && tid == 0) { ws[0] = 0.0f; ((unsigned*)ws)[1] = 0u; }
    if (blk < 4) {
        int k = blk * 256 + tid;
        const float* row = cb + (size_t)k * EMB_DIM;
        float half[2];
#pragma unroll
        for (int h = 0; h < 2; ++h) {
            const float* a = row + h * 128;
            float r[8];
#pragma unroll
            for (int j = 0; j < 8; ++j) r[j] = __fmul_rn(a[j], a[j]);
            for (int i = 8; i < 128; i += 8)
#pragma unroll
                for (int j = 0; j < 8; ++j)
                    r[j] = __fadd_rn(r[j], __fmul_rn(a[i + j], a[i + j]));
            half[h] = __fadd_rn(__fadd_rn(__fadd_rn(r[0], r[1]), __fadd_rn(r[2], r[3])),
                                __fadd_rn(__fadd_rn(r[4], r[5]), __fadd_rn(r[6], r[7])));
        }
        ws[WS_CNORM_OFF + k] = __fadd_rn(half[0], half[1]);
    } else if (blk < 132) {
        int n = (blk - 4) * 256 + tid;
        int b = n >> 10, p = n & 1023;
        const float* base = z + (size_t)b * EMB_DIM * HW + p;
        float half[2];
#pragma unroll
        for (int h = 0; h < 2; ++h) {
            float r[8];
#pragma unroll
            for (int j = 0; j < 8; ++j) {
                float v = base[(size_t)(h * 128 + j) * HW];
                r[j] = __fmul_rn(v, v);
            }
            for (int i = 8; i < 128; i += 8)
#pragma unroll
                for (int j = 0; j < 8; ++j) {
                    float v = base[(size_t)(h * 128 + i + j) * HW];
                    r[j] = __fadd_rn(r[j], __fmul_rn(v, v));
                }
            half[h] = __fadd_rn(__fadd_rn(__fadd_rn(r[0], r[1]), __fadd_rn(r[2], r[3])),
                                __fadd_rn(__fadd_rn(r[4], r[5]), __fadd_rn(r[6], r[7])));
        }
        ws[WS_ZNORM_OFF + n] = __fadd_rn(half[0], half[1]);
    } else if (blk < 164) {
        int i = (blk - 132) * 256 + tid;           // 0..8191, 4 ints each
        int4 zero = {0, 0, 0, 0};
        *(int4*)((int*)out + CNT_IOFF + (size_t)i * 4) = zero;
    } else {
        unsigned u = (unsigned)(blk - 164) * 256 + tid;   // 0..65535
        int lane = u & 63;
        int nt   = (u >> 6) & 15;
        int h    = (u >> 10) & 1;
        int c    = (u >> 11) & 7;
        int s    = (u >> 14) & 3;
        int code = s * 256 + nt * 16 + (lane & 15);
        int d0   = c * 32 + (lane >> 4) * 8;
        const float* cr = cb + (size_t)code * EMB_DIM + d0;
        u16x8 v;
#pragma unroll
        for (int j = 0; j < 8; ++j) {
            float x = cr[j];
            unsigned short hi = f2bf_rne(x);
            v[j] = (h == 0) ? hi : f2bf_rne(x - bf2f(hi));
        }
        unsigned short* Bt = (unsigned short*)out;
        *(u16x8*)(Bt + ((((size_t)(s * 8 + c) * 2 + h) * 16 + nt) * 64 + lane) * 8) = v;
    }
}

// ---------------------------------------------------------------------------
// K1: MFMA candidate filter. Block = 64 queries x one 256-code slab.
// dot_mfma = A_hi*B_hi + A_lo*B_hi + A_hi*B_lo (bf16, RNE splits), K=256 in
// 8 chunks of 32. s = c2 - 2*dot. Slab-local min via shfl+LDS; every code with
// s <= min + T_FILT is appended to the query's candidate list (atomicAdd).
// Layouts (guide-verified for mfma_f32_16x16x32_bf16):
//   A frag: lane l holds A[m=l&15][k=(l>>4)*8+j]
//   B frag: lane l holds B[k=(l>>4)*8+j][n=l&15]   (standard CDNA symmetric)
//   C/D:    row m = (l>>4)*4+reg, col n = l&15
__global__ __launch_bounds__(256) void k_filter(const float* __restrict__ z,
                                                const float* __restrict__ ws,
                                                float* __restrict__ out) {
    __shared__ __attribute__((aligned(16))) unsigned short A_lds[2 * 4 * 64 * 8];   // 8 KB
    __shared__ __attribute__((aligned(16))) unsigned short B_lds[2 * 16 * 64 * 8];  // 32 KB
    __shared__ float wm[4 * 64];
    __shared__ float minq[64];

    const int tid = threadIdx.x;
    const int w = tid >> 6;            // wave 0..3
    const int l = tid & 63;
    const int s = blockIdx.y;          // code slab 0..3
    const int nq0 = blockIdx.x * 64;
    const int b  = nq0 >> 10;
    const int p0 = nq0 & 1023;
    const int p  = l;                  // staging position

    const float* zb = z + (size_t)b * EMB_DIM * HW + p0;   // elem (d,p): zb[d*HW+p]
    const u16x8* Bt8 = (const u16x8*)out;
    const float* cn = ws + WS_CNORM_OFF;

    // prefetch chunk 0
    float zpre[8];
    u16x8 bpre[8];
#pragma unroll
    for (int j = 0; j < 8; ++j) zpre[j] = zb[(size_t)(w * 8 + j) * HW + p];
#pragma unroll
    for (int i = 0; i < 8; ++i) bpre[i] = Bt8[(size_t)(s * 8) * 2048 + i * 256 + tid];

    f32x4 acc[4][4];
#pragma unroll
    for (int mt = 0; mt < 4; ++mt)
#pragma unroll
        for (int ntl = 0; ntl < 4; ++ntl) acc[mt][ntl] = (f32x4)(0.0f);

#pragma unroll 1
    for (int c = 0; c < 8; ++c) {
        __syncthreads();
        // stage A (convert to hi/lo bf16, RNE)
        {
            u16x8 vhi, vlo;
#pragma unroll
            for (int j = 0; j < 8; ++j) {
                unsigned short hi = f2bf_rne(zpre[j]);
                vhi[j] = hi;
                vlo[j] = f2bf_rne(zpre[j] - bf2f(hi));
            }
            *(u16x8*)&A_lds[((0 * 4 + w) * 64 + p) * 8] = vhi;
            *(u16x8*)&A_lds[((1 * 4 + w) * 64 + p) * 8] = vlo;
        }
        // stage B (pre-tiled copy)
#pragma unroll
        for (int i = 0; i < 8; ++i)
            *(u16x8*)&B_lds[(size_t)(i * 256 + tid) * 8] = bpre[i];
        // prefetch chunk c+1
        if (c < 7) {
#pragma unroll
            for (int j = 0; j < 8; ++j)
                zpre[j] = zb[(size_t)((c + 1) * 32 + w * 8 + j) * HW + p];
#pragma unroll
            for (int i = 0; i < 8; ++i)
                bpre[i] = Bt8[(size_t)(s * 8 + c + 1) * 2048 + i * 256 + tid];
        }
        __syncthreads();

        bf16x8 bh[4], bl[4];
#pragma unroll
        for (int ntl = 0; ntl < 4; ++ntl) {
            int nt = w * 4 + ntl;
            bh[ntl] = *(const bf16x8*)&B_lds[((0 * 16 + nt) * 64 + l) * 8];
            bl[ntl] = *(const bf16x8*)&B_lds[((1 * 16 + nt) * 64 + l) * 8];
        }
#pragma unroll
        for (int mt = 0; mt < 4; ++mt) {
            bf16x8 ah = *(const bf16x8*)&A_lds[((0 * 4 + (l >> 4)) * 64 + mt * 16 + (l & 15)) * 8];
            bf16x8 al = *(const bf16x8*)&A_lds[((1 * 4 + (l >> 4)) * 64 + mt * 16 + (l & 15)) * 8];
#pragma unroll
            for (int ntl = 0; ntl < 4; ++ntl) {
                acc[mt][ntl] = __builtin_amdgcn_mfma_f32_16x16x32_bf16(ah, bh[ntl], acc[mt][ntl], 0, 0, 0);
                acc[mt][ntl] = __builtin_amdgcn_mfma_f32_16x16x32_bf16(al, bh[ntl], acc[mt][ntl], 0, 0, 0);
                acc[mt][ntl] = __builtin_amdgcn_mfma_f32_16x16x32_bf16(ah, bl[ntl], acc[mt][ntl], 0, 0, 0);
            }
        }
    }

    // epilogue: s = c2 - 2*dot, slab-local min, candidate append
    float c2[4];
#pragma unroll
    for (int ntl = 0; ntl < 4; ++ntl)
        c2[ntl] = cn[s * 256 + (w * 4 + ntl) * 16 + (l & 15)];

    float vmin[4][4];
#pragma unroll
    for (int mt = 0; mt < 4; ++mt)
#pragma unroll
        for (int reg = 0; reg < 4; ++reg) vmin[mt][reg] = 3.4e38f;
#pragma unroll
    for (int mt = 0; mt < 4; ++mt)
#pragma unroll
        for (int ntl = 0; ntl < 4; ++ntl)
#pragma unroll
            for (int reg = 0; reg < 4; ++reg) {
                float sv = fmaf(-2.0f, acc[mt][ntl][reg], c2[ntl]);
                acc[mt][ntl][reg] = sv;
                vmin[mt][reg] = fminf(vmin[mt][reg], sv);
            }
#pragma unroll
    for (int msk = 1; msk < 16; msk <<= 1)
#pragma unroll
        for (int mt = 0; mt < 4; ++mt)
#pragma unroll
            for (int reg = 0; reg < 4; ++reg)
                vmin[mt][reg] = fminf(vmin[mt][reg], __shfl_xor(vmin[mt][reg], msk, 64));
    if ((l & 15) == 0) {
#pragma unroll
        for (int mt = 0; mt < 4; ++mt)
#pragma unroll
            for (int reg = 0; reg < 4; ++reg)
                wm[w * 64 + mt * 16 + (l >> 4) * 4 + reg] = vmin[mt][reg];
    }
    __syncthreads();
    if (tid < 64)
        minq[tid] = fminf(fminf(wm[tid], wm[64 + tid]), fminf(wm[128 + tid], wm[192 + tid]));
    __syncthreads();

    int* cnt  = (int*)out + CNT_IOFF;
    int* cand = (int*)out + CAND_IOFF;
#pragma unroll
    for (int mt = 0; mt < 4; ++mt)
#pragma unroll
        for (int reg = 0; reg < 4; ++reg) {
            int m = mt * 16 + (l >> 4) * 4 + reg;
            float thr = minq[m] + T_FILT;
#pragma unroll
            for (int ntl = 0; ntl < 4; ++ntl) {
                if (acc[mt][ntl][reg] <= thr) {
                    int kg = s * 256 + (w * 4 + ntl) * 16 + (l & 15);
                    int nq = nq0 + m;
                    int slot = atomicAdd(&cnt[nq], 1);
                    if (slot < CAND_CAP) cand[(size_t)nq * CAND_CAP + slot] = kg;
                }
            }
        }
}

// ---------------------------------------------------------------------------
// K2: exact rescore of candidates: the bit-proven reference recipe —
// serial ascending-d fma dot, fold fl(fl(z2+c2) - fl(2*dot)), first-index ties.
__global__ __launch_bounds__(256) void k_rescore(const float* __restrict__ z,
                                                 const float* __restrict__ cb,
                                                 const float* __restrict__ ws,
                                                 float* __restrict__ out) {
    int n = blockIdx.x * 256 + threadIdx.x;
    int b = n >> 10, p = n & 1023;
    const float* zc = z + (size_t)b * EMB_DIM * HW + p;    // elem d: zc[d*HW]
    const int* cnt  = (const int*)out + CNT_IOFF;
    const int* cand = (const int*)out + CAND_IOFF;
    const float* cn = ws + WS_CNORM_OFF;
    float z2 = ws[WS_ZNORM_OFF + n];
    int c = cnt[n];
    float best = 3.4e38f; int bestk = NUM_EMB;
    if (c <= CAND_CAP) {
        for (int i0 = 0; i0 < c; i0 += 4) {
            int nc = c - i0; if (nc > 4) nc = 4;
            int kk[4];
#pragma unroll
            for (int j = 0; j < 4; ++j)
                kk[j] = cand[(size_t)n * CAND_CAP + i0 + (j < nc ? j : nc - 1)];
            float dot[4] = {0.0f, 0.0f, 0.0f, 0.0f};
            const float* r0 = cb + (size_t)kk[0] * EMB_DIM;
            const float* r1 = cb + (size_t)kk[1] * EMB_DIM;
            const float* r2 = cb + (size_t)kk[2] * EMB_DIM;
            const float* r3 = cb + (size_t)kk[3] * EMB_DIM;
#pragma unroll 4
            for (int d = 0; d < EMB_DIM; ++d) {
                float zv = zc[(size_t)d * HW];
                dot[0] = fmaf(zv, r0[d], dot[0]);
                dot[1] = fmaf(zv, r1[d], dot[1]);
                dot[2] = fmaf(zv, r2[d], dot[2]);
                dot[3] = fmaf(zv, r3[d], dot[3]);
            }
            for (int j = 0; j < nc; ++j) {
                float t1 = __fadd_rn(z2, cn[kk[j]]);
                float sv = __fadd_rn(t1, __fmul_rn(-2.0f, dot[j]));
                if (sv < best || (sv == best && kk[j] < bestk)) { best = sv; bestk = kk[j]; }
            }
        }
    } else {           // overflow fallback (astronomically rare): exact full scan
        for (int k = 0; k < NUM_EMB; ++k) {
            const float* r = cb + (size_t)k * EMB_DIM;
            float dot = 0.0f;
            for (int d = 0; d < EMB_DIM; ++d) dot = fmaf(zc[(size_t)d * HW], r[d], dot);
            float t1 = __fadd_rn(z2, cn[k]);
            float sv = __fadd_rn(t1, __fmul_rn(-2.0f, dot));
            if (sv < best) { best = sv; bestk = k; }   // ascending k: strict < keeps first
        }
    }
    out[IDX_OFF + n] = (float)bestk;
}

// ---------------------------------------------------------------------------
// K3: gather z_q via LDS-staged codebook rows, straight-through write
// out = fl(z + fl(z_q - z)), loss partials + fused final scale via ticket.
__global__ __launch_bounds__(256) void k_gather(const float* __restrict__ z,
                                                const float* __restrict__ cb,
                                                float* __restrict__ out,
                                                float* __restrict__ ws) {
    __shared__ float s_cb[64][65];
    __shared__ int   s_idx[64];
    __shared__ float s_red[4];
    const int tid = threadIdx.x;
    const int b  = blockIdx.x >> 4;
    const int p0 = (blockIdx.x & 15) * 64;

    if (tid < 64)
        s_idx[tid] = (int)out[IDX_OFF + (size_t)b * HW + p0 + tid];
    __syncthreads();

    const int p    = tid & 63;
    const int cgrp = tid >> 6;
    const int row  = tid >> 2;
    const int q4   = tid & 3;
    const float* zrow = z   + (size_t)b * EMB_DIM * HW + p0 + p;
    float*       orow = out + (size_t)b * EMB_DIM * HW + p0 + p;

    float acc = 0.0f;
#pragma unroll 1
    for (int d0 = 0; d0 < EMB_DIM; d0 += 64) {
        const float* cr = cb + (size_t)s_idx[row] * EMB_DIM + d0;
#pragma unroll
        for (int pass = 0; pass < 4; ++pass) {
            int c = q4 * 4 + pass * 16;
            *(float4*)(&s_cb[row][c]) = *(const float4*)(cr + c);
        }
        __syncthreads();
#pragma unroll
        for (int j = 0; j < 16; ++j) {
            int c = cgrp * 16 + j;
            float zq = s_cb[p][c];
            float zv = zrow[(size_t)(d0 + c) * HW];
            float d  = zq - zv;
            orow[(size_t)(d0 + c) * HW] = zv + d;
            acc += d * d;
        }
        __syncthreads();
    }
#pragma unroll
    for (int off = 32; off > 0; off >>= 1) acc += __shfl_down(acc, off, 64);
    if ((tid & 63) == 0) s_red[tid >> 6] = acc;
    __syncthreads();
    if (tid == 0) {
        atomicAdd(ws, s_red[0] + s_red[1] + s_red[2] + s_red[3]);
        __threadfence();
        unsigned old = atomicAdd((unsigned int*)ws + 1, 1u);
        if (old == 511u) {
            float total = atomicAdd(ws, 0.0f);
            out[LOSS_OFF] = 1.25f * (total * (1.0f / 8388608.0f));
        }
    }
}

// ---------------------------------------------------------------------------
extern "C" void kernel_launch(void* const* d_in, const int* in_sizes, int n_in,
                              void* d_out, int out_size, void* d_ws, size_t ws_size,
                              hipStream_t stream) {
    const float* z  = (const float*)d_in[0];
    const float* cb = (const float*)d_in[1];
    float* out = (float*)d_out;
    float* ws  = (float*)d_ws;

    k_prep   <<<420, 256, 0, stream>>>(z, cb, ws, out);
    k_filter <<<dim3(512, 4), 256, 0, stream>>>(z, ws, out);
    k_rescore<<<128, 256, 0, stream>>>(z, cb, ws, out);
    k_gather <<<512, 256, 0, stream>>>(z, cb, out, ws);
}